// Round 14
// baseline (27.273 us; speedup 1.0000x reference)
//
#include <hip/hip_runtime.h>

#define EMBED 512
#define NTOK 8192
#define MT 16            // tokens per block (one MFMA M-tile)
#define NB1 6            // GEMM1 N-frags (96 cols = 16 fc1w^T | 64 W1 | 4 b1 | pad)
#define KS1 16           // GEMM1 K-steps (512/32)
#define NB2 32           // GEMM2 N-frags (512 cols)
#define KS2 3            // GEMM2 K-steps (96/32; rows 68..95 zero)
#define B1ELEMS (KS1 * NB1 * 64 * 8)   // 49152 halves = 96 KB
#define B2ELEMS (KS2 * NB2 * 64 * 8)   // 49152
#define ZR 104           // z LDS pitch (halves)

using half8   = __attribute__((ext_vector_type(8))) _Float16;
using half2_t = __attribute__((ext_vector_type(2))) _Float16;
using f32x4   = __attribute__((ext_vector_type(4))) float;
using uint4_t = __attribute__((ext_vector_type(4))) unsigned;

#define MFMA16(a, b, c) __builtin_amdgcn_mfma_f32_16x16x32_f16((a), (b), (c), 0, 0, 0)

__device__ __forceinline__ unsigned pkrtz_u(float a, float b) {
    return __builtin_bit_cast(unsigned, __builtin_amdgcn_cvt_pkrtz(a, b));
}
__device__ __forceinline__ half2_t pkrtz(float a, float b) {
    return __builtin_bit_cast(half2_t, __builtin_amdgcn_cvt_pkrtz(a, b));
}
__device__ __forceinline__ half8 pack8(float4 a0, float4 a1) {
    uint4_t u;
    u.x = pkrtz_u(a0.x, a0.y);
    u.y = pkrtz_u(a0.z, a0.w);
    u.z = pkrtz_u(a1.x, a1.y);
    u.w = pkrtz_u(a1.z, a1.w);
    return __builtin_bit_cast(half8, u);
}

// ---------------------------------------------------------------------------
// prep (proven): pack B1 [512x96] and B2 [96x512] f16 in MFMA B-frag order.
// frag(ks,nf): lane l holds B[k=ks*32+(l>>4)*8+i][col=nf*16+(l&15)],
// flat [ks][nf][lane][i] -> coalesced 16B/lane loads in main.
// ---------------------------------------------------------------------------
__global__ __launch_bounds__(512) void prep(const float* __restrict__ fc1w,
                                            const float* __restrict__ fc2w,
                                            const float* __restrict__ fc2b,
                                            _Float16* __restrict__ b1f,
                                            _Float16* __restrict__ b2f)
{
    const int g = blockIdx.x * 512 + threadIdx.x;      // 0..12287 slots
    float v[8];
    if (g < B1ELEMS / 8) {
        const int lane = g & 63, rest = g >> 6;
        const int nf = rest % NB1, kstep = rest / NB1;
        const int k0 = kstep * 32 + ((lane >> 4) << 3);
        const int c  = nf * 16 + (lane & 15);
        if (c < 16) {
            const float4* p = reinterpret_cast<const float4*>(fc1w + c * EMBED + k0);
            float4 a = p[0], b = p[1];
            v[0]=a.x; v[1]=a.y; v[2]=a.z; v[3]=a.w; v[4]=b.x; v[5]=b.y; v[6]=b.z; v[7]=b.w;
        } else if (c < 80) {
            const int cc = c - 16;
            const float* p = fc2w + k0 * 64 + (cc >> 4) * 16 + (cc & 15);
            #pragma unroll
            for (int i = 0; i < 8; ++i) v[i] = p[i * 64];
        } else if (c < 84) {
            const float* p = fc2b + k0 * 4 + (c - 80);
            #pragma unroll
            for (int i = 0; i < 8; ++i) v[i] = p[i * 4];
        } else {
            #pragma unroll
            for (int i = 0; i < 8; ++i) v[i] = 0.f;
        }
        half8 h;
        #pragma unroll
        for (int i = 0; i < 8; ++i) h[i] = (_Float16)v[i];
        *reinterpret_cast<half8*>(b1f + g * 8) = h;
    } else if (g < (B1ELEMS + B2ELEMS) / 8) {
        const int g2 = g - B1ELEMS / 8;
        const int lane = g2 & 63, rest = g2 >> 6;
        const int nf = rest & 31, kstep = rest >> 5;
        const int k0 = kstep * 32 + ((lane >> 4) << 3);
        const int e  = nf * 16 + (lane & 15);
        if (k0 < 64) {
            const float4* p = reinterpret_cast<const float4*>(
                fc2w + (2048 + (k0 >> 4) * 512 + e) * 16 + (k0 & 15));
            float4 a = p[0], b = p[1];
            v[0]=a.x; v[1]=a.y; v[2]=a.z; v[3]=a.w; v[4]=b.x; v[5]=b.y; v[6]=b.z; v[7]=b.w;
        } else if (k0 == 64) {
            #pragma unroll
            for (int i = 0; i < 8; ++i)
                v[i] = (i < 4) ? fc2b[2048 + i * 512 + e] : 0.f;
        } else {
            #pragma unroll
            for (int i = 0; i < 8; ++i) v[i] = 0.f;
        }
        half8 h;
        #pragma unroll
        for (int i = 0; i < 8; ++i) h[i] = (_Float16)v[i];
        *reinterpret_cast<half8*>(b2f + g2 * 8) = h;
    }
}

// ---------------------------------------------------------------------------
// main (cycle-lean): MT=16, 512 thr (8 waves), grid 512, 2 blocks/CU target.
//  - waves 0-5: B1 frag column nf=wv in 16 half8 regs (L2 prefetch)
//  - GEMM1 A-frags DIRECT from global x (coalesced dwordx4 pairs + pkrtz)
//  - c1 spill -> b2r prefetch (12 half8) -> barrier -> glue(64 thr) -> barrier
//  - GEMM2 from regs -> coalesced store.  Only 2 barriers, ~10 KB LDS.
// ---------------------------------------------------------------------------
__global__ __launch_bounds__(512, 4) void hyper_main(const float* __restrict__ x,
                                                     const float* __restrict__ fc1b,
                                                     const _Float16* __restrict__ b1f,
                                                     const _Float16* __restrict__ b2f,
                                                     float* __restrict__ out)
{
    __shared__ float    c1s[MT][100];       // 6.4 KB
    __shared__ _Float16 zh[MT][ZR];         // 3.3 KB

    const int tid  = threadIdx.x;
    const int lane = tid & 63;
    const int wv   = tid >> 6;              // 0..7
    const int rowA = lane & 15;
    const int kgrp = lane >> 4;             // 0..3
    const long tok0 = (long)blockIdx.x * MT;
    const bool hasG1 = (wv < 6);
    const int  nfA   = hasG1 ? wv : 0;

    // ---- B1 frag prefetch (waves 0-5): 16 half8 = 64 VGPR, L2 ---------------
    half8 b1a[KS1];
    if (hasG1) {
        #pragma unroll
        for (int ks = 0; ks < KS1; ++ks)
            b1a[ks] = *reinterpret_cast<const half8*>(b1f + ((ks * NB1 + nfA) * 64 + lane) * 8);
    }

    // ================= GEMM1: A direct from global x =========================
    f32x4 accA = {0.f, 0.f, 0.f, 0.f};
    if (hasG1) {
        const float* xrow = x + (tok0 + rowA) * EMBED + kgrp * 8;
        #pragma unroll
        for (int ks = 0; ks < KS1; ++ks) {
            const float4* xp = reinterpret_cast<const float4*>(xrow + ks * 32);
            float4 a0 = xp[0], a1 = xp[1];
            accA = MFMA16(pack8(a0, a1), b1a[ks], accA);
        }
        #pragma unroll
        for (int r = 0; r < 4; ++r) c1s[kgrp * 4 + r][nfA * 16 + rowA] = accA[r];
    }

    // ---- b2 prefetch (all waves): 12 half8 = 48 VGPR, overlaps barrier+glue -
    half8 b2r[KS2][4];
    #pragma unroll
    for (int ks = 0; ks < KS2; ++ks)
        #pragma unroll
        for (int f = 0; f < 4; ++f)
            b2r[ks][f] = *reinterpret_cast<const half8*>(
                b2f + ((ks * NB2 + wv * 4 + f) * 64 + lane) * 8);

    __syncthreads();

    // ================= glue (tid<64): h, y1, Z = (y1 (x) h | y1 | 0) =========
    if (tid < 64) {
        const int t = tid & 15, j = tid >> 4;
        float h[16];
        #pragma unroll
        for (int k = 0; k < 16; ++k) h[k] = fmaxf(c1s[t][k] + fc1b[k], 0.f);
        float y1 = c1s[t][80 + j];
        #pragma unroll
        for (int k = 0; k < 16; ++k) y1 = fmaf(c1s[t][16 + j * 16 + k], h[k], y1);
        y1 = fmaxf(y1, 0.f);
        #pragma unroll
        for (int k = 0; k < 16; k += 2) {
            half2_t p = pkrtz(y1 * h[k], y1 * h[k + 1]);
            *reinterpret_cast<half2_t*>(&zh[t][j * 16 + k]) = p;
        }
        zh[t][64 + j] = (_Float16)y1;
        #pragma unroll
        for (int p = 0; p < 7; ++p) zh[t][68 + j * 7 + p] = (_Float16)0.f;
    }
    __syncthreads();

    // ================= GEMM2: Z[16x96] * B2[96x512], B in regs ===============
    f32x4 acc2[4];
    #pragma unroll
    for (int f = 0; f < 4; ++f) acc2[f] = (f32x4){0.f, 0.f, 0.f, 0.f};

    #pragma unroll
    for (int ks = 0; ks < KS2; ++ks) {
        half8 az = *reinterpret_cast<const half8*>(&zh[rowA][ks * 32 + kgrp * 8]);
        #pragma unroll
        for (int f = 0; f < 4; ++f) acc2[f] = MFMA16(az, b2r[ks][f], acc2[f]);
    }

    // ================= relu + store (coalesced 64B lines) ====================
    #pragma unroll
    for (int f = 0; f < 4; ++f) {
        const int e = (wv * 4 + f) * 16 + rowA;
        #pragma unroll
        for (int r = 0; r < 4; ++r) {
            out[(tok0 + kgrp * 4 + r) * EMBED + e] = fmaxf(acc2[f][r], 0.f);
        }
    }
}

extern "C" void kernel_launch(void* const* d_in, const int* in_sizes, int n_in,
                              void* d_out, int out_size, void* d_ws, size_t ws_size,
                              hipStream_t stream) {
    const float* x    = (const float*)d_in[0];
    const float* fc1w = (const float*)d_in[1];
    const float* fc1b = (const float*)d_in[2];
    const float* fc2w = (const float*)d_in[3];
    const float* fc2b = (const float*)d_in[4];
    float* out = (float*)d_out;

    _Float16* b1f = (_Float16*)d_ws;                   // 96 KB
    _Float16* b2f = b1f + B1ELEMS;                     // 96 KB

    prep<<<dim3((B1ELEMS + B2ELEMS) / 8 / 512), dim3(512), 0, stream>>>(fc1w, fc2w, fc2b, b1f, b2f);
    hyper_main<<<dim3(NTOK / MT), dim3(512), 0, stream>>>(x, fc1b, b1f, b2f, out);
}

// Round 16
// 18.947 us; speedup vs baseline: 1.4394x; 1.4394x over previous
//
#include <hip/hip_runtime.h>

#define EMBED 512
#define NTOK 8192
#define MT 16            // tokens per tile (one MFMA M-tile)
#define TPB 2            // tiles per block (pipelined)
#define NB1 6            // GEMM1 N-frags (96 cols = 16 fc1w^T | 64 W1 | 4 b1 | pad)
#define KS1 16           // GEMM1 K-steps (512/32)
#define NB2 32           // GEMM2 N-frags (512 cols)
#define KS2 3            // GEMM2 K-steps (96/32; rows 68..95 zero)
#define B1ELEMS (KS1 * NB1 * 64 * 8)   // 49152
#define B2ELEMS (KS2 * NB2 * 64 * 8)   // 49152
#define XR 520           // x LDS pitch (halves)
#define ZR 104           // z LDS pitch (halves)

using half8   = __attribute__((ext_vector_type(8))) _Float16;
using half2_t = __attribute__((ext_vector_type(2))) _Float16;
using f32x4   = __attribute__((ext_vector_type(4))) float;

#define MFMA16(a, b, c) __builtin_amdgcn_mfma_f32_16x16x32_f16((a), (b), (c), 0, 0, 0)

__device__ __forceinline__ unsigned pkrtz_u(float a, float b) {
    return __builtin_bit_cast(unsigned, __builtin_amdgcn_cvt_pkrtz(a, b));
}
__device__ __forceinline__ half2_t pkrtz(float a, float b) {
    return __builtin_bit_cast(half2_t, __builtin_amdgcn_cvt_pkrtz(a, b));
}

// ---------------------------------------------------------------------------
// prep (R3, proven): pack B1 [512x96] and B2 [96x512] f16 in MFMA B-frag order.
// frag(ks,nf): lane l holds B[k=ks*32+(l>>4)*8+i][col=nf*16+(l&15)]
// ---------------------------------------------------------------------------
__global__ __launch_bounds__(256) void prep(const float* __restrict__ fc1w,
                                            const float* __restrict__ fc2w,
                                            const float* __restrict__ fc2b,
                                            _Float16* __restrict__ b1f,
                                            _Float16* __restrict__ b2f)
{
    const int i = blockIdx.x * 256 + threadIdx.x;      // 0..49151
    {
        const int elem = i & 7, lane = (i >> 3) & 63, rest = i >> 9;
        const int nf = rest % NB1, kstep = rest / NB1;
        const int krow = kstep * 32 + (lane >> 4) * 8 + elem;         // e
        const int c = nf * 16 + (lane & 15);
        float v;
        if (c < 16)      v = fc1w[c * EMBED + krow];
        else if (c < 80) { int cc = c - 16; v = fc2w[(krow * 4 + (cc >> 4)) * 16 + (cc & 15)]; }
        else if (c < 84) v = fc2b[krow * 4 + (c - 80)];
        else             v = 0.f;
        b1f[i] = (_Float16)v;
    }
    {
        const int elem = i & 7, lane = (i >> 3) & 63, rest = i >> 9;
        const int nf = rest & 31, kstep = rest >> 5;
        const int krow = kstep * 32 + (lane >> 4) * 8 + elem;         // 0..95
        const int e = nf * 16 + (lane & 15);
        float v;
        if (krow < 64)      v = fc2w[(2048 + (krow >> 4) * 512 + e) * 16 + (krow & 15)];
        else if (krow < 68) v = fc2b[2048 + (krow - 64) * 512 + e];
        else                v = 0.f;
        b2f[i] = (_Float16)v;
    }
}

// ---------------------------------------------------------------------------
// main: 256 blocks x 2 tiles (32 tokens). 8 waves, (512,2) so no register
// remat (R11/R14 lesson). B1/B2 frags prefetched ONCE, reused for both tiles;
// both x-tiles' HBM loads issued up-front so tile-1 latency hides under
// tile-0 compute. Per tile: 2048 float4 = 4 iters x 512 threads.
// ---------------------------------------------------------------------------
__global__ __launch_bounds__(512, 2) void hyper_main(const float* __restrict__ x,
                                                     const float* __restrict__ fc1b,
                                                     const _Float16* __restrict__ b1f,
                                                     const _Float16* __restrict__ b2f,
                                                     float* __restrict__ out)
{
    __shared__ _Float16 xh[TPB][MT][XR];    // 33.3 KB
    __shared__ float    c1s[MT][100];       // 6.4 KB
    __shared__ _Float16 zh[MT][ZR];         // 3.3 KB

    const int tid  = threadIdx.x;
    const int lane = tid & 63;
    const int wv   = tid >> 6;              // 0..7
    const int rowA = lane & 15;
    const int kgrp = lane >> 4;             // 0..3
    const long tok0 = (long)blockIdx.x * (MT * TPB);
    const bool hasG1 = (wv < 6);
    const int  nfA   = hasG1 ? wv : 0;

    // ---- issue BOTH x-tile loads (HBM) up-front: 2048 float4 each -----------
    float4 xr0[4], xr1[4];
    {
        const float4* xg = reinterpret_cast<const float4*>(x + tok0 * EMBED);
        #pragma unroll
        for (int i = 0; i < 4; ++i) xr0[i] = xg[tid + i * 512];
        #pragma unroll
        for (int i = 0; i < 4; ++i) xr1[i] = xg[2048 + tid + i * 512];
    }

    // ---- B1 frag prefetch (waves 0-5): 16 half8, reused for both tiles ------
    half8 b1a[KS1];
    if (hasG1) {
        #pragma unroll
        for (int ks = 0; ks < KS1; ++ks)
            b1a[ks] = *reinterpret_cast<const half8*>(b1f + ((ks * NB1 + nfA) * 64 + lane) * 8);
    }
    // ---- B2 frag prefetch (all waves): 12 half8, reused for both tiles ------
    half8 b2r[KS2][4];
    #pragma unroll
    for (int ks = 0; ks < KS2; ++ks)
        #pragma unroll
        for (int f = 0; f < 4; ++f)
            b2r[ks][f] = *reinterpret_cast<const half8*>(
                b2f + ((ks * NB2 + wv * 4 + f) * 64 + lane) * 8);

    // ---- stage both tiles -> f16 LDS (2048 float4 per tile) -----------------
    #pragma unroll
    for (int i = 0; i < 4; ++i) {
        const int idx = tid + i * 512;                 // 0..2047
        const int t = idx >> 7, e4 = idx & 127;
        uint2 w;
        w.x = pkrtz_u(xr0[i].x, xr0[i].y);
        w.y = pkrtz_u(xr0[i].z, xr0[i].w);
        *reinterpret_cast<uint2*>(&xh[0][t][e4 * 4]) = w;
    }
    #pragma unroll
    for (int i = 0; i < 4; ++i) {
        const int idx = tid + i * 512;
        const int t = idx >> 7, e4 = idx & 127;
        uint2 w;
        w.x = pkrtz_u(xr1[i].x, xr1[i].y);
        w.y = pkrtz_u(xr1[i].z, xr1[i].w);
        *reinterpret_cast<uint2*>(&xh[1][t][e4 * 4]) = w;
    }
    __syncthreads();

    // ================= pipelined 2-tile loop =================================
    #pragma unroll
    for (int tt = 0; tt < TPB; ++tt) {
        // ---- GEMM1: X[16x512] * B1[512x96] (waves 0-5) ----------------------
        if (hasG1) {
            f32x4 accA = {0.f, 0.f, 0.f, 0.f};
            #pragma unroll
            for (int ks = 0; ks < KS1; ++ks) {
                half8 a = *reinterpret_cast<const half8*>(&xh[tt][rowA][ks * 32 + kgrp * 8]);
                accA = MFMA16(a, b1a[ks], accA);
            }
            #pragma unroll
            for (int r = 0; r < 4; ++r) c1s[kgrp * 4 + r][nfA * 16 + rowA] = accA[r];
        }
        __syncthreads();

        // ---- glue (tid<64): h, y1, Z = (y1 (x) h | y1 | 0) ------------------
        if (tid < 64) {
            const int t = tid & 15, j = tid >> 4;
            float h[16];
            #pragma unroll
            for (int k = 0; k < 16; ++k) h[k] = fmaxf(c1s[t][k] + fc1b[k], 0.f);
            float y1 = c1s[t][80 + j];
            #pragma unroll
            for (int k = 0; k < 16; ++k) y1 = fmaf(c1s[t][16 + j * 16 + k], h[k], y1);
            y1 = fmaxf(y1, 0.f);
            #pragma unroll
            for (int k = 0; k < 16; k += 2) {
                half2_t p = pkrtz(y1 * h[k], y1 * h[k + 1]);
                *reinterpret_cast<half2_t*>(&zh[t][j * 16 + k]) = p;
            }
            zh[t][64 + j] = (_Float16)y1;
            #pragma unroll
            for (int p = 0; p < 7; ++p) zh[t][68 + j * 7 + p] = (_Float16)0.f;
        }
        __syncthreads();

        // ---- GEMM2: Z[16x96] * B2[96x512] -----------------------------------
        f32x4 acc2[4];
        #pragma unroll
        for (int f = 0; f < 4; ++f) acc2[f] = (f32x4){0.f, 0.f, 0.f, 0.f};
        #pragma unroll
        for (int ks = 0; ks < KS2; ++ks) {
            half8 az = *reinterpret_cast<const half8*>(&zh[rowA][ks * 32 + kgrp * 8]);
            #pragma unroll
            for (int f = 0; f < 4; ++f) acc2[f] = MFMA16(az, b2r[ks][f], acc2[f]);
        }

        // ---- relu + store ----------------------------------------------------
        #pragma unroll
        for (int f = 0; f < 4; ++f) {
            const int e = (wv * 4 + f) * 16 + rowA;
            #pragma unroll
            for (int r = 0; r < 4; ++r) {
                out[(tok0 + tt * MT + kgrp * 4 + r) * EMBED + e] = fmaxf(acc2[f][r], 0.f);
            }
        }
        // barrier safety across iterations:
        //  - c1s: GEMM1(t1) writes happen after the post-glue(t0) barrier,
        //    which postdates glue(t0)'s c1s reads.
        //  - zh: glue(t1) writes happen after the post-GEMM1(t1) barrier,
        //    which postdates GEMM2(t0)'s zh reads.
    }
}

extern "C" void kernel_launch(void* const* d_in, const int* in_sizes, int n_in,
                              void* d_out, int out_size, void* d_ws, size_t ws_size,
                              hipStream_t stream) {
    const float* x    = (const float*)d_in[0];
    const float* fc1w = (const float*)d_in[1];
    const float* fc1b = (const float*)d_in[2];
    const float* fc2w = (const float*)d_in[3];
    const float* fc2b = (const float*)d_in[4];
    float* out = (float*)d_out;

    _Float16* b1f = (_Float16*)d_ws;                   // 96 KB
    _Float16* b2f = b1f + B1ELEMS;                     // 96 KB

    prep<<<dim3(B1ELEMS / 256), dim3(256), 0, stream>>>(fc1w, fc2w, fc2b, b1f, b2f);
    hyper_main<<<dim3(NTOK / (MT * TPB)), dim3(512), 0, stream>>>(x, fc1b, b1f, b2f, out);
}